// Round 1
// baseline (4826.192 us; speedup 1.0000x reference)
//
#include <hip/hip_runtime.h>
#include <math.h>

#define NT 4096
#define NA 4096
#define NS 1024
#define NALL 9216

// ---------------- small prep kernels ----------------

__global__ void k_weights(const float* __restrict__ sg, const float* __restrict__ ff,
                          const float* __restrict__ f4, float* __restrict__ w8) {
  // single thread: softmax(sg_agg_w), softmax(f_agg_f_w), softmax(f_agg_w)
  float m = fmaxf(sg[0], sg[1]);
  float e0 = expf(sg[0] - m), e1 = expf(sg[1] - m);
  w8[0] = e0 / (e0 + e1); w8[1] = e1 / (e0 + e1);
  m = fmaxf(ff[0], ff[1]);
  e0 = expf(ff[0] - m); e1 = expf(ff[1] - m);
  w8[2] = e0 / (e0 + e1); w8[3] = e1 / (e0 + e1);
  m = fmaxf(fmaxf(f4[0], f4[1]), fmaxf(f4[2], f4[3]));
  float a0 = expf(f4[0] - m), a1 = expf(f4[1] - m), a2 = expf(f4[2] - m), a3 = expf(f4[3] - m);
  float s = a0 + a1 + a2 + a3;
  w8[4] = a0 / s; w8[5] = a1 / s; w8[6] = a2 / s; w8[7] = a3 / s;
}

// V[r, h*D+d] = (src[r,d]*w[h,d]) / max(||src[r,:]*w[h,:]||, 1e-12)
__global__ void k_rownorm(const float* __restrict__ src, int D,
                          const float* __restrict__ w, float* __restrict__ V) {
  int r = blockIdx.x;
  int t = threadIdx.x;  // 64 threads = 1 wave
  const float* x = src + (size_t)r * D;
  float* out = V + (size_t)r * (2 * D);
  for (int h = 0; h < 2; ++h) {
    float ss = 0.f;
    for (int d = t; d < D; d += 64) {
      float y = x[d] * w[h * D + d];
      ss = fmaf(y, y, ss);
    }
    for (int off = 32; off; off >>= 1) ss += __shfl_xor(ss, off);
    float nrm = fmaxf(sqrtf(ss), 1e-12f);
    for (int d = t; d < D; d += 64) {
      float y = x[d] * w[h * D + d];
      out[h * D + d] = y / nrm;
    }
  }
}

// out[r,0:128] = sum_c adj[r, colbase+c] * feats[c, 0:128]   (adj 0.5% dense)
__global__ void k_spmm128(const float* __restrict__ adj, int colbase, int ncols,
                          const float* __restrict__ feats, float* __restrict__ out) {
  __shared__ float a_s[128];
  int r = blockIdx.x, t = threadIdx.x;  // 128 threads
  const float* arow = adj + (size_t)r * NALL + colbase;
  float acc = 0.f;
  for (int c0 = 0; c0 < ncols; c0 += 128) {
    __syncthreads();
    a_s[t] = arow[c0 + t];
    __syncthreads();
    for (int cc = 0; cc < 128; ++cc) {
      float a = a_s[cc];
      if (a != 0.f) acc = fmaf(a, feats[(size_t)(c0 + cc) * 128 + t], acc);
    }
  }
  out[(size_t)r * 128 + t] = acc;
}

// out[r,0:64] = sum_c adj[r, colbase+c] * S[c,0:64] + bias
__global__ void k_spmm64(const float* __restrict__ adj, int colbase, int ncols,
                         const float* __restrict__ S, const float* __restrict__ bias,
                         float* __restrict__ out) {
  __shared__ float a_s[128];
  int r = blockIdx.x, t = threadIdx.x;  // 64 threads
  const float* arow = adj + (size_t)r * NALL + colbase;
  float acc = 0.f;
  for (int c0 = 0; c0 < ncols; c0 += 128) {
    __syncthreads();
    a_s[t] = arow[c0 + t];
    a_s[t + 64] = arow[c0 + t + 64];
    __syncthreads();
    for (int cc = 0; cc < 128; ++cc) {
      float a = a_s[cc];
      if (a != 0.f) acc = fmaf(a, S[(size_t)(c0 + cc) * 64 + t], acc);
    }
  }
  out[(size_t)r * 64 + t] = acc + bias[t];
}

// ---------------- 64x64 tile dot-product core (f32, 4x4 micro) ----------------

__device__ __forceinline__ void tile_dot(const float* __restrict__ V, int ldv, int K,
                                         int r0, int c0, int tid, int tx, int ty,
                                         float (*As)[68], float (*Bs)[68],
                                         float acc[4][4]) {
  for (int kc = 0; kc < K; kc += 64) {
    __syncthreads();
#pragma unroll
    for (int m = 0; m < 16; ++m) {
      int lin = tid + 256 * m;
      int row = lin >> 6, col = lin & 63;
      As[col][row] = V[(size_t)(r0 + row) * ldv + kc + col];  // transposed: [k][row]
      Bs[col][row] = V[(size_t)(c0 + row) * ldv + kc + col];
    }
    __syncthreads();
#pragma unroll 8
    for (int k = 0; k < 64; ++k) {
      float a[4], b[4];
#pragma unroll
      for (int i = 0; i < 4; ++i) a[i] = As[k][ty * 4 + i];
#pragma unroll
      for (int j = 0; j < 4; ++j) b[j] = Bs[k][tx * 4 + j];
#pragma unroll
      for (int i = 0; i < 4; ++i)
#pragma unroll
        for (int j = 0; j < 4; ++j)
          acc[i][j] = fmaf(a[i], b[j], acc[i][j]);
    }
  }
}

// sim[r,c] = thresh(0.5 * V[r].V[c])
__global__ __launch_bounds__(256) void k_simmat(const float* __restrict__ V, int R, int K,
                                                float th, float* __restrict__ out) {
  __shared__ float As[64][68], Bs[64][68];
  int r0 = blockIdx.y * 64, c0 = blockIdx.x * 64;
  int tid = threadIdx.x, tx = tid & 15, ty = tid >> 4;
  float acc[4][4] = {};
  tile_dot(V, K, K, r0, c0, tid, tx, ty, As, Bs, acc);
#pragma unroll
  for (int i = 0; i < 4; ++i)
#pragma unroll
    for (int j = 0; j < 4; ++j) {
      float s = 0.5f * acc[i][j];
      out[(size_t)(r0 + ty * 4 + i) * R + (c0 + tx * 4 + j)] = (s < th) ? 0.f : s;
    }
}

// cs[c] += sum_r thresh(0.5 * V[r].V[c])  over this tile's rows
__global__ __launch_bounds__(256) void k_colsum(const float* __restrict__ V, int K, float th,
                                                float* __restrict__ cs) {
  __shared__ float As[64][68], Bs[64][68];
  __shared__ float red[16][64];
  int r0 = blockIdx.y * 64, c0 = blockIdx.x * 64;
  int tid = threadIdx.x, tx = tid & 15, ty = tid >> 4;
  float acc[4][4] = {};
  tile_dot(V, K, K, r0, c0, tid, tx, ty, As, Bs, acc);
  float part[4] = {0.f, 0.f, 0.f, 0.f};
#pragma unroll
  for (int i = 0; i < 4; ++i)
#pragma unroll
    for (int j = 0; j < 4; ++j) {
      float s = 0.5f * acc[i][j];
      if (s >= th) part[j] += s;
    }
#pragma unroll
  for (int j = 0; j < 4; ++j) red[ty][tx * 4 + j] = part[j];
  __syncthreads();
  if (tid < 64) {
    float s = 0.f;
#pragma unroll
    for (int q = 0; q < 16; ++q) s += red[q][tid];
    atomicAdd(&cs[c0 + tid], s);
  }
}

// per-column combine coefficients from colsums + softmaxed agg weights
__global__ void k_coef(const float* __restrict__ cs, const float* __restrict__ w8,
                       float* __restrict__ coef) {
  int c = blockIdx.x * 256 + threadIdx.x;
  if (c >= NT) return;
  float csg = cs[c], cspap = cs[NT + c], cspsp = cs[2 * NT + c];
  float csf0 = cs[3 * NT + c], csf1 = cs[4 * NT + c];
  float css0 = cs[5 * NT + c], css1 = cs[6 * NT + c];
  float wS0 = w8[0], wS1 = w8[1], wFF0 = w8[2], wFF1 = w8[3];
  float wF0 = w8[4], wF1 = w8[5], wF2 = w8[6], wF3 = w8[7];
  auto mx = [](float x) { return fmaxf(x, 1e-12f); };
  auto ind = [](float x) { return x > 0.f ? 1.f : 0.f; };
  float cssem = wS0 * ind(cspap) + wS1 * ind(cspsp);
  float csfp = wFF0 * ind(csf0) + wFF1 * ind(csf1);
  float cstt = wFF0 * ind(css0) + wFF1 * ind(css1);
  coef[c]          = wF0 / mx(csg);
  coef[NT + c]     = wF1 * wS0 / (mx(cspap) * mx(cssem));
  coef[2 * NT + c] = wF1 * wS1 / (mx(cspsp) * mx(cssem));
  coef[3 * NT + c] = wF2 * wFF0 / (mx(csf0) * mx(csfp));
  coef[4 * NT + c] = wF2 * wFF1 / (mx(csf1) * mx(csfp));
  coef[5 * NT + c] = wF3 * wFF0 / (mx(css0) * mx(cstt));
  coef[6 * NT + c] = wF3 * wFF1 / (mx(css1) * mx(cstt));
}

// sym[r,c] = sum_k (coef_k[r]+coef_k[c]) * M_k[r,c]; also finalcs[c] += colsum
__global__ __launch_bounds__(256) void k_combine(
    const float* __restrict__ Vg, const float* __restrict__ Vpap, const float* __restrict__ Vpsp,
    const float* __restrict__ Vf0, const float* __restrict__ Vf1,
    const float* __restrict__ Vs0, const float* __restrict__ Vs1,
    const float* __restrict__ coef, float* __restrict__ outAdj, float* __restrict__ finalcs) {
  __shared__ float As[64][68], Bs[64][68];
  __shared__ float red[16][64];
  int r0 = blockIdx.y * 64, c0 = blockIdx.x * 64;
  int tid = threadIdx.x, tx = tid & 15, ty = tid >> 4;
  const float* Vs[7] = {Vg, Vpap, Vpsp, Vf0, Vf1, Vs0, Vs1};
  const int Ks[7] = {256, 128, 128, 256, 256, 128, 128};
  const float ths[7] = {0.1f, 0.1f, 0.1f, 0.2f, 0.2f, 0.1f, 0.1f};
  float comb[4][4] = {};
  for (int ch = 0; ch < 7; ++ch) {
    float acc[4][4] = {};
    tile_dot(Vs[ch], Ks[ch], Ks[ch], r0, c0, tid, tx, ty, As, Bs, acc);
    float cr[4], cc_[4];
#pragma unroll
    for (int i = 0; i < 4; ++i) cr[i] = coef[ch * NT + r0 + ty * 4 + i];
#pragma unroll
    for (int j = 0; j < 4; ++j) cc_[j] = coef[ch * NT + c0 + tx * 4 + j];
    float th = ths[ch];
#pragma unroll
    for (int i = 0; i < 4; ++i)
#pragma unroll
      for (int j = 0; j < 4; ++j) {
        float s = 0.5f * acc[i][j];
        if (s >= th) comb[i][j] = fmaf(cr[i] + cc_[j], s, comb[i][j]);
      }
  }
  float part[4] = {0.f, 0.f, 0.f, 0.f};
#pragma unroll
  for (int i = 0; i < 4; ++i)
#pragma unroll
    for (int j = 0; j < 4; ++j) {
      outAdj[(size_t)(r0 + ty * 4 + i) * NT + c0 + tx * 4 + j] = comb[i][j];
      part[j] += comb[i][j];
    }
#pragma unroll
  for (int j = 0; j < 4; ++j) red[ty][tx * 4 + j] = part[j];
  __syncthreads();
  if (tid < 64) {
    float s = 0.f;
#pragma unroll
    for (int q = 0; q < 16; ++q) s += red[q][tid];
    atomicAdd(&finalcs[c0 + tid], s);
  }
}

__global__ void k_scale(float* __restrict__ adj, const float* __restrict__ finalcs) {
  size_t idx = (size_t)blockIdx.x * 256 + threadIdx.x;
  int c = (int)(idx & (NT - 1));
  adj[idx] = adj[idx] / fmaxf(finalcs[c], 1e-12f);
}

// C[M,64] = A[M,K] @ B[K,64] (+bias, relu optional)
__global__ __launch_bounds__(256) void k_gemm_n64(const float* __restrict__ A, int K,
                                                  const float* __restrict__ B,
                                                  float* __restrict__ C,
                                                  const float* __restrict__ bias, int relu) {
  __shared__ float As[64][68], Bs[64][68];
  int r0 = blockIdx.x * 64;
  int tid = threadIdx.x, tx = tid & 15, ty = tid >> 4;
  float acc[4][4] = {};
  for (int kc = 0; kc < K; kc += 64) {
    __syncthreads();
#pragma unroll
    for (int m = 0; m < 16; ++m) {
      int lin = tid + 256 * m;
      int row = lin >> 6, col = lin & 63;
      As[col][row] = A[(size_t)(r0 + row) * K + kc + col];   // [k][row]
      Bs[row][col] = B[(size_t)(kc + row) * 64 + col];       // [k][col]
    }
    __syncthreads();
#pragma unroll 8
    for (int k = 0; k < 64; ++k) {
      float a[4], b[4];
#pragma unroll
      for (int i = 0; i < 4; ++i) a[i] = As[k][ty * 4 + i];
#pragma unroll
      for (int j = 0; j < 4; ++j) b[j] = Bs[k][tx * 4 + j];
#pragma unroll
      for (int i = 0; i < 4; ++i)
#pragma unroll
        for (int j = 0; j < 4; ++j)
          acc[i][j] = fmaf(a[i], b[j], acc[i][j]);
    }
  }
#pragma unroll
  for (int i = 0; i < 4; ++i)
#pragma unroll
    for (int j = 0; j < 4; ++j) {
      float v = acc[i][j];
      if (bias) v += bias[tx * 4 + j];
      if (relu) v = fmaxf(v, 0.f);
      C[(size_t)(r0 + ty * 4 + i) * 64 + tx * 4 + j] = v;
    }
}

// P2[r,0:3] = X1[r,:] @ W2
__global__ void k_p2(const float* __restrict__ X1, const float* __restrict__ W2,
                     float* __restrict__ P2) {
  int r = blockIdx.x * 64 + threadIdx.x;
  float a0 = 0.f, a1 = 0.f, a2 = 0.f;
#pragma unroll 8
  for (int k = 0; k < 64; ++k) {
    float x = X1[(size_t)r * 64 + k];
    a0 = fmaf(x, W2[k * 3 + 0], a0);
    a1 = fmaf(x, W2[k * 3 + 1], a1);
    a2 = fmaf(x, W2[k * 3 + 2], a2);
  }
  P2[r * 4 + 0] = a0; P2[r * 4 + 1] = a1; P2[r * 4 + 2] = a2;
}

// logits[r,:] = log_softmax(adj[r,:] @ P2 + b2)
__global__ void k_out(const float* __restrict__ adj, const float* __restrict__ P2,
                      const float* __restrict__ b2, float* __restrict__ logits) {
  int r = blockIdx.x, t = threadIdx.x;  // 64 threads
  const float* arow = adj + (size_t)r * NT;
  float a0 = 0.f, a1 = 0.f, a2 = 0.f;
  for (int c = t; c < NT; c += 64) {
    float a = arow[c];
    a0 = fmaf(a, P2[c * 4 + 0], a0);
    a1 = fmaf(a, P2[c * 4 + 1], a1);
    a2 = fmaf(a, P2[c * 4 + 2], a2);
  }
  for (int off = 32; off; off >>= 1) {
    a0 += __shfl_xor(a0, off);
    a1 += __shfl_xor(a1, off);
    a2 += __shfl_xor(a2, off);
  }
  if (t == 0) {
    a0 += b2[0]; a1 += b2[1]; a2 += b2[2];
    float m = fmaxf(a0, fmaxf(a1, a2));
    float lse = m + logf(expf(a0 - m) + expf(a1 - m) + expf(a2 - m));
    logits[r * 3 + 0] = a0 - lse;
    logits[r * 3 + 1] = a1 - lse;
    logits[r * 3 + 2] = a2 - lse;
  }
}

// ---------------- host ----------------

extern "C" void kernel_launch(void* const* d_in, const int* in_sizes, int n_in,
                              void* d_out, int out_size, void* d_ws, size_t ws_size,
                              hipStream_t stream) {
  (void)in_sizes; (void)n_in; (void)out_size; (void)ws_size;
  const float* features = (const float*)d_in[0];
  const float* adj      = (const float*)d_in[1];
  const float* mp_pap   = (const float*)d_in[2];
  const float* mp_psp   = (const float*)d_in[3];
  const float* fgo_w    = (const float*)d_in[6];
  const float* fpo_w    = (const float*)d_in[7];
  const float* sgg_pap_w = (const float*)d_in[8];
  const float* sgg_psp_w = (const float*)d_in[9];
  const float* sg_agg_w  = (const float*)d_in[10];
  const float* f_agg_f_w = (const float*)d_in[11];
  const float* f_agg_w   = (const float*)d_in[12];
  const float* topo_W_a  = (const float*)d_in[13];
  const float* topo_b_a  = (const float*)d_in[14];
  const float* topo_W_s  = (const float*)d_in[15];
  const float* topo_b_s  = (const float*)d_in[16];
  const float* fgt_w_a   = (const float*)d_in[17];
  const float* fgt_w_s   = (const float*)d_in[18];
  const float* gcn_W1    = (const float*)d_in[19];
  const float* gcn_b1    = (const float*)d_in[20];
  const float* gcn_W2    = (const float*)d_in[21];
  const float* gcn_b2    = (const float*)d_in[22];

  float* logits = (float*)d_out;
  float* adjOut = (float*)d_out + (size_t)NT * 3;  // 4096x4096; doubles as sim_a scratch

  float* ws = (float*)d_ws;
  size_t o = 0;
  float* Vg   = ws + o; o += (size_t)NT * 256;
  float* Vfa  = ws + o; o += (size_t)NA * 256;
  float* Vf0  = ws + o; o += (size_t)NT * 256;
  float* Vf1  = ws + o; o += (size_t)NT * 256;
  float* Vpap = ws + o; o += (size_t)NT * 128;
  float* Vpsp = ws + o; o += (size_t)NT * 128;
  float* Vs0  = ws + o; o += (size_t)NT * 128;
  float* Vs1  = ws + o; o += (size_t)NT * 128;
  float* fpa  = ws + o; o += (size_t)NT * 128;
  float* fps  = ws + o; o += (size_t)NT * 128;
  float* Vfs  = ws + o; o += (size_t)NS * 256;
  float* topoA = ws + o; o += (size_t)NT * 64;
  float* topoS = ws + o; o += (size_t)NT * 64;
  float* Sa   = ws + o; o += (size_t)NA * 64;
  float* Ss   = ws + o; o += (size_t)NS * 64;
  float* simS = ws + o; o += (size_t)NS * NS;
  float* H1   = ws + o; o += (size_t)NT * 64;
  float* X1   = ws + o; o += (size_t)NT * 64;
  float* P2   = ws + o; o += (size_t)NT * 4;
  float* cs   = ws + o; o += (size_t)7 * NT;
  float* fcs  = ws + o; o += NT;           // contiguous with cs (memset together)
  float* coef = ws + o; o += (size_t)7 * NT;
  float* w8   = ws + o; o += 8;

  hipMemsetAsync(cs, 0, (size_t)8 * NT * sizeof(float), stream);
  k_weights<<<1, 1, 0, stream>>>(sg_agg_w, f_agg_f_w, f_agg_w, w8);

  // normalized head-weighted feature vectors
  k_rownorm<<<NT, 64, 0, stream>>>(features, 128, fgo_w, Vg);
  k_rownorm<<<NT, 64, 0, stream>>>(mp_pap, 64, sgg_pap_w, Vpap);
  k_rownorm<<<NT, 64, 0, stream>>>(mp_psp, 64, sgg_psp_w, Vpsp);
  k_rownorm<<<NA, 64, 0, stream>>>(features + (size_t)NT * 128, 128, fgo_w, Vfa);
  k_rownorm<<<NS, 64, 0, stream>>>(features + (size_t)(NT + NA) * 128, 128, fgo_w, Vfs);

  // feat_prop = ori_g @ fmat_r  (sparse)
  k_spmm128<<<NT, 128, 0, stream>>>(adj, NT, NA, features + (size_t)NT * 128, fpa);
  k_spmm128<<<NT, 128, 0, stream>>>(adj, NT + NA, NS, features + (size_t)(NT + NA) * 128, fps);
  k_rownorm<<<NT, 64, 0, stream>>>(fpa, 128, fpo_w, Vf0);
  k_rownorm<<<NT, 64, 0, stream>>>(fps, 128, fpo_w, Vf1);

  // sim_r matrices (authors one lives in d_out scratch), then S_r = sim_r @ topo_W
  dim3 g64(64, 64), g16(16, 16);
  k_simmat<<<g64, 256, 0, stream>>>(Vfa, NA, 256, 0.1f, adjOut);
  k_simmat<<<g16, 256, 0, stream>>>(Vfs, NS, 256, 0.1f, simS);
  k_gemm_n64<<<NA / 64, 256, 0, stream>>>(adjOut, NA, topo_W_a, Sa, nullptr, 0);
  k_gemm_n64<<<NS / 64, 256, 0, stream>>>(simS, NS, topo_W_s, Ss, nullptr, 0);

  // topo_hid = ori_g @ S_r + b   (associativity: (ori_g@sim)@W == ori_g@(sim@W))
  k_spmm64<<<NT, 64, 0, stream>>>(adj, NT, NA, Sa, topo_b_a, topoA);
  k_spmm64<<<NT, 64, 0, stream>>>(adj, NT + NA, NS, Ss, topo_b_s, topoS);
  k_rownorm<<<NT, 64, 0, stream>>>(topoA, 64, fgt_w_a, Vs0);
  k_rownorm<<<NT, 64, 0, stream>>>(topoS, 64, fgt_w_s, Vs1);

  // pass 1: per-channel column sums
  k_colsum<<<g64, 256, 0, stream>>>(Vg, 256, 0.1f, cs + 0 * NT);
  k_colsum<<<g64, 256, 0, stream>>>(Vpap, 128, 0.1f, cs + 1 * NT);
  k_colsum<<<g64, 256, 0, stream>>>(Vpsp, 128, 0.1f, cs + 2 * NT);
  k_colsum<<<g64, 256, 0, stream>>>(Vf0, 256, 0.2f, cs + 3 * NT);
  k_colsum<<<g64, 256, 0, stream>>>(Vf1, 256, 0.2f, cs + 4 * NT);
  k_colsum<<<g64, 256, 0, stream>>>(Vs0, 128, 0.1f, cs + 5 * NT);
  k_colsum<<<g64, 256, 0, stream>>>(Vs1, 128, 0.1f, cs + 6 * NT);
  k_coef<<<NT / 256, 256, 0, stream>>>(cs, w8, coef);

  // pass 2: combine + symmetrize (coef[r]+coef[c]) -> unnormalized new_adj + finalcs
  k_combine<<<g64, 256, 0, stream>>>(Vg, Vpap, Vpsp, Vf0, Vf1, Vs0, Vs1, coef, adjOut, fcs);
  k_scale<<<(NT * NT) / 256, 256, 0, stream>>>(adjOut, fcs);

  // GCN
  k_gemm_n64<<<NT / 64, 256, 0, stream>>>(features, 128, gcn_W1, H1, nullptr, 0);
  k_gemm_n64<<<NT / 64, 256, 0, stream>>>(adjOut, NT, H1, X1, gcn_b1, 1);
  k_p2<<<NT / 64, 64, 0, stream>>>(X1, gcn_W2, P2);
  k_out<<<NT, 64, 0, stream>>>(adjOut, P2, gcn_b2, logits);
}

// Round 2
// 1312.373 us; speedup vs baseline: 3.6775x; 3.6775x over previous
//
#include <hip/hip_runtime.h>
#include <math.h>

#define NT 4096
#define NA 4096
#define NS 1024
#define NALL 9216

typedef __bf16 bf16_t;
typedef bf16_t bf16x8 __attribute__((ext_vector_type(8)));
typedef float f32x4 __attribute__((ext_vector_type(4)));

static __device__ __forceinline__ f32x4 mfma_bf16(bf16x8 a, bf16x8 b, f32x4 c) {
  return __builtin_amdgcn_mfma_f32_16x16x32_bf16(a, b, c, 0, 0, 0);
}

// ---------------- small prep kernels ----------------

__global__ void k_weights(const float* __restrict__ sg, const float* __restrict__ ff,
                          const float* __restrict__ f4, float* __restrict__ w8) {
  float m = fmaxf(sg[0], sg[1]);
  float e0 = expf(sg[0] - m), e1 = expf(sg[1] - m);
  w8[0] = e0 / (e0 + e1); w8[1] = e1 / (e0 + e1);
  m = fmaxf(ff[0], ff[1]);
  e0 = expf(ff[0] - m); e1 = expf(ff[1] - m);
  w8[2] = e0 / (e0 + e1); w8[3] = e1 / (e0 + e1);
  m = fmaxf(fmaxf(f4[0], f4[1]), fmaxf(f4[2], f4[3]));
  float a0 = expf(f4[0] - m), a1 = expf(f4[1] - m), a2 = expf(f4[2] - m), a3 = expf(f4[3] - m);
  float s = a0 + a1 + a2 + a3;
  w8[4] = a0 / s; w8[5] = a1 / s; w8[6] = a2 / s; w8[7] = a3 / s;
}

// V[r, h*D+d] = (src[r,d]*w[h,d]) / max(||src[r,:]*w[h,:]||, 1e-12), output bf16
__global__ void k_rownorm(const float* __restrict__ src, int D,
                          const float* __restrict__ w, bf16_t* __restrict__ V) {
  int r = blockIdx.x;
  int t = threadIdx.x;  // 64 threads = 1 wave
  const float* x = src + (size_t)r * D;
  bf16_t* out = V + (size_t)r * (2 * D);
  for (int h = 0; h < 2; ++h) {
    float ss = 0.f;
    for (int d = t; d < D; d += 64) {
      float y = x[d] * w[h * D + d];
      ss = fmaf(y, y, ss);
    }
    for (int off = 32; off; off >>= 1) ss += __shfl_xor(ss, off);
    float nrm = fmaxf(sqrtf(ss), 1e-12f);
    for (int d = t; d < D; d += 64) {
      float y = x[d] * w[h * D + d];
      out[h * D + d] = (bf16_t)(y / nrm);
    }
  }
}

// out[r,0:128] = sum_c adj[r, colbase+c] * feats[c, 0:128]   (adj ~0.5% dense; ballot scan)
__global__ void k_spmm128(const float* __restrict__ adj, int colbase, int ncols,
                          const float* __restrict__ feats, float* __restrict__ out) {
  int r = blockIdx.x, t = threadIdx.x, wv = t >> 6, lane = t & 63;  // 128 thr = 2 waves
  const float* arow = adj + (size_t)r * NALL + colbase;
  float acc0 = 0.f, acc1 = 0.f;
  for (int c0 = wv * 64; c0 < ncols; c0 += 128) {
    float a = arow[c0 + lane];
    unsigned long long m = __ballot(a != 0.f);
    while (m) {
      int b = __builtin_ctzll(m); m &= m - 1;
      float v = __shfl(a, b);
      const float* f = feats + (size_t)(c0 + b) * 128;
      acc0 = fmaf(v, f[lane], acc0);
      acc1 = fmaf(v, f[lane + 64], acc1);
    }
  }
  __shared__ float red[2][128];
  red[wv][lane] = acc0; red[wv][lane + 64] = acc1;
  __syncthreads();
  if (t < 128) out[(size_t)r * 128 + t] = red[0][t] + red[1][t];
}

// out[r,0:64] = sum_c adj[r, colbase+c] * S[c,0:64] + bias
__global__ void k_spmm64(const float* __restrict__ adj, int colbase, int ncols,
                         const float* __restrict__ S, const float* __restrict__ bias,
                         float* __restrict__ out) {
  int r = blockIdx.x, t = threadIdx.x, wv = t >> 6, lane = t & 63;  // 128 thr = 2 waves
  const float* arow = adj + (size_t)r * NALL + colbase;
  float acc = 0.f;
  for (int c0 = wv * 64; c0 < ncols; c0 += 128) {
    float a = arow[c0 + lane];
    unsigned long long m = __ballot(a != 0.f);
    while (m) {
      int b = __builtin_ctzll(m); m &= m - 1;
      float v = __shfl(a, b);
      acc = fmaf(v, S[(size_t)(c0 + b) * 64 + lane], acc);
    }
  }
  __shared__ float red[2][64];
  red[wv][lane] = acc;
  __syncthreads();
  if (t < 64) out[(size_t)r * 64 + t] = red[0][t] + red[1][t] + bias[t];
}

// Wt[n][k] = (bf16) W[k][n]   (W: [K][64] f32)
__global__ void k_transp(const float* __restrict__ W, int K, bf16_t* __restrict__ Wt) {
  int idx = blockIdx.x * 256 + threadIdx.x;
  int n = idx & 63, k = idx >> 6;
  if (k < K) Wt[(size_t)n * K + k] = (bf16_t)W[(size_t)k * 64 + n];
}

// ---------------- MFMA Gram tile core ----------------
// Wave computes 64x64 tile of V * V^T via 4x4 fragments of 16x16x32.
// Both operands loaded as ROWS of V with identical lane patterns (k-perm invariant).

static __device__ __forceinline__ void gram_tile(const bf16_t* __restrict__ V, int ldv, int K,
                                                 int r0w, int c0w, int rq, int kq,
                                                 f32x4 acc[4][4]) {
  const bf16_t* Ap = V + (size_t)(r0w + rq) * ldv + kq * 8;
  const bf16_t* Bp = V + (size_t)(c0w + rq) * ldv + kq * 8;
#pragma unroll 2
  for (int kc = 0; kc < K; kc += 32) {
    bf16x8 a[4], b[4];
#pragma unroll
    for (int f = 0; f < 4; ++f) {
      a[f] = *(const bf16x8*)(Ap + (size_t)(f * 16) * ldv + kc);
      b[f] = *(const bf16x8*)(Bp + (size_t)(f * 16) * ldv + kc);
    }
#pragma unroll
    for (int fi = 0; fi < 4; ++fi)
#pragma unroll
      for (int fj = 0; fj < 4; ++fj)
        acc[fi][fj] = mfma_bf16(a[fi], b[fj], acc[fi][fj]);
  }
}

// sim[r,c] = thresh(0.5 * V[r].V[c]) -> bf16 output, row length R
__global__ __launch_bounds__(256, 2) void k_gram_sim(const bf16_t* __restrict__ V, int R, int K,
                                                     float th, bf16_t* __restrict__ out) {
  int tid = threadIdx.x, lane = tid & 63, w = tid >> 6;
  int wr = w >> 1, wc = w & 1, rq = lane & 15, kq = lane >> 4;
  int r0w = blockIdx.y * 128 + wr * 64, c0w = blockIdx.x * 128 + wc * 64;
  f32x4 acc[4][4];
#pragma unroll
  for (int i = 0; i < 4; ++i)
#pragma unroll
    for (int j = 0; j < 4; ++j) acc[i][j] = 0.f;
  gram_tile(V, K, K, r0w, c0w, rq, kq, acc);
#pragma unroll
  for (int fi = 0; fi < 4; ++fi)
#pragma unroll
    for (int fj = 0; fj < 4; ++fj)
#pragma unroll
      for (int reg = 0; reg < 4; ++reg) {
        float s = 0.5f * acc[fi][fj][reg];
        int row = r0w + fi * 16 + kq * 4 + reg;
        int col = c0w + fj * 16 + rq;
        out[(size_t)row * R + col] = (bf16_t)((s < th) ? 0.f : s);
      }
}

// all-7-channel thresholded column sums -> cs[7][NT] (atomic)
__global__ __launch_bounds__(256, 2) void k_colsum_all(
    const bf16_t* __restrict__ Vg, const bf16_t* __restrict__ Vpap, const bf16_t* __restrict__ Vpsp,
    const bf16_t* __restrict__ Vf0, const bf16_t* __restrict__ Vf1,
    const bf16_t* __restrict__ Vs0, const bf16_t* __restrict__ Vs1,
    float* __restrict__ cs) {
  int tid = threadIdx.x, lane = tid & 63, w = tid >> 6;
  int wr = w >> 1, wc = w & 1, rq = lane & 15, kq = lane >> 4;
  int r0w = blockIdx.y * 128 + wr * 64, c0w = blockIdx.x * 128 + wc * 64;
  const bf16_t* const Vp[7] = {Vg, Vpap, Vpsp, Vf0, Vf1, Vs0, Vs1};
  const int Ks[7] = {256, 128, 128, 256, 256, 128, 128};
  const float ths[7] = {0.1f, 0.1f, 0.1f, 0.2f, 0.2f, 0.1f, 0.1f};
#pragma unroll
  for (int ch = 0; ch < 7; ++ch) {
    f32x4 acc[4][4];
#pragma unroll
    for (int i = 0; i < 4; ++i)
#pragma unroll
      for (int j = 0; j < 4; ++j) acc[i][j] = 0.f;
    gram_tile(Vp[ch], Ks[ch], Ks[ch], r0w, c0w, rq, kq, acc);
    float th = ths[ch];
    float part[4] = {0.f, 0.f, 0.f, 0.f};
#pragma unroll
    for (int fi = 0; fi < 4; ++fi)
#pragma unroll
      for (int fj = 0; fj < 4; ++fj)
#pragma unroll
        for (int reg = 0; reg < 4; ++reg) {
          float s = 0.5f * acc[fi][fj][reg];
          if (s >= th) part[fj] += s;
        }
#pragma unroll
    for (int fj = 0; fj < 4; ++fj) {
      float p = part[fj];
      p += __shfl_xor(p, 16);
      p += __shfl_xor(p, 32);
      if (kq == 0) atomicAdd(&cs[ch * NT + c0w + fj * 16 + rq], p);
    }
  }
}

// per-column combine coefficients from colsums + softmaxed agg weights
__global__ void k_coef(const float* __restrict__ cs, const float* __restrict__ w8,
                       float* __restrict__ coef) {
  int c = blockIdx.x * 256 + threadIdx.x;
  if (c >= NT) return;
  float csg = cs[c], cspap = cs[NT + c], cspsp = cs[2 * NT + c];
  float csf0 = cs[3 * NT + c], csf1 = cs[4 * NT + c];
  float css0 = cs[5 * NT + c], css1 = cs[6 * NT + c];
  float wS0 = w8[0], wS1 = w8[1], wFF0 = w8[2], wFF1 = w8[3];
  float wF0 = w8[4], wF1 = w8[5], wF2 = w8[6], wF3 = w8[7];
  auto mx = [](float x) { return fmaxf(x, 1e-12f); };
  auto ind = [](float x) { return x > 0.f ? 1.f : 0.f; };
  float cssem = wS0 * ind(cspap) + wS1 * ind(cspsp);
  float csfp = wFF0 * ind(csf0) + wFF1 * ind(csf1);
  float cstt = wFF0 * ind(css0) + wFF1 * ind(css1);
  coef[c]          = wF0 / mx(csg);
  coef[NT + c]     = wF1 * wS0 / (mx(cspap) * mx(cssem));
  coef[2 * NT + c] = wF1 * wS1 / (mx(cspsp) * mx(cssem));
  coef[3 * NT + c] = wF2 * wFF0 / (mx(csf0) * mx(csfp));
  coef[4 * NT + c] = wF2 * wFF1 / (mx(csf1) * mx(csfp));
  coef[5 * NT + c] = wF3 * wFF0 / (mx(css0) * mx(cstt));
  coef[6 * NT + c] = wF3 * wFF1 / (mx(css1) * mx(cstt));
}

// sym[r,c] = sum_ch (coef[r]+coef[c]) * M_ch[r,c]; also finalcs[c] (atomic)
__global__ __launch_bounds__(256, 2) void k_combine(
    const bf16_t* __restrict__ Vg, const bf16_t* __restrict__ Vpap, const bf16_t* __restrict__ Vpsp,
    const bf16_t* __restrict__ Vf0, const bf16_t* __restrict__ Vf1,
    const bf16_t* __restrict__ Vs0, const bf16_t* __restrict__ Vs1,
    const float* __restrict__ coef, float* __restrict__ outAdj, float* __restrict__ finalcs) {
  int tid = threadIdx.x, lane = tid & 63, w = tid >> 6;
  int wr = w >> 1, wc = w & 1, rq = lane & 15, kq = lane >> 4;
  int r0w = blockIdx.y * 128 + wr * 64, c0w = blockIdx.x * 128 + wc * 64;
  const bf16_t* const Vp[7] = {Vg, Vpap, Vpsp, Vf0, Vf1, Vs0, Vs1};
  const int Ks[7] = {256, 128, 128, 256, 256, 128, 128};
  const float ths[7] = {0.1f, 0.1f, 0.1f, 0.2f, 0.2f, 0.1f, 0.1f};
  f32x4 comb[4][4];
#pragma unroll
  for (int i = 0; i < 4; ++i)
#pragma unroll
    for (int j = 0; j < 4; ++j) comb[i][j] = 0.f;
#pragma unroll
  for (int ch = 0; ch < 7; ++ch) {
    f32x4 acc[4][4];
#pragma unroll
    for (int i = 0; i < 4; ++i)
#pragma unroll
      for (int j = 0; j < 4; ++j) acc[i][j] = 0.f;
    gram_tile(Vp[ch], Ks[ch], Ks[ch], r0w, c0w, rq, kq, acc);
    float th = ths[ch];
    const float* cf = coef + ch * NT;
    f32x4 cr[4];
    float cc_[4];
#pragma unroll
    for (int fi = 0; fi < 4; ++fi) cr[fi] = *(const f32x4*)&cf[r0w + fi * 16 + kq * 4];
#pragma unroll
    for (int fj = 0; fj < 4; ++fj) cc_[fj] = cf[c0w + fj * 16 + rq];
#pragma unroll
    for (int fi = 0; fi < 4; ++fi)
#pragma unroll
      for (int fj = 0; fj < 4; ++fj)
#pragma unroll
        for (int reg = 0; reg < 4; ++reg) {
          float s = 0.5f * acc[fi][fj][reg];
          if (s >= th) comb[fi][fj][reg] = fmaf(cr[fi][reg] + cc_[fj], s, comb[fi][fj][reg]);
        }
  }
  float part[4] = {0.f, 0.f, 0.f, 0.f};
#pragma unroll
  for (int fi = 0; fi < 4; ++fi)
#pragma unroll
    for (int fj = 0; fj < 4; ++fj)
#pragma unroll
      for (int reg = 0; reg < 4; ++reg) {
        float v = comb[fi][fj][reg];
        int row = r0w + fi * 16 + kq * 4 + reg;
        int col = c0w + fj * 16 + rq;
        outAdj[(size_t)row * NT + col] = v;
        part[fj] += v;
      }
#pragma unroll
  for (int fj = 0; fj < 4; ++fj) {
    float p = part[fj];
    p += __shfl_xor(p, 16);
    p += __shfl_xor(p, 32);
    if (kq == 0) atomicAdd(&finalcs[c0w + fj * 16 + rq], p);
  }
}

__global__ void k_scale(float* __restrict__ adj, const float* __restrict__ finalcs) {
  size_t idx = (size_t)blockIdx.x * 256 + threadIdx.x;
  int c = (int)(idx & (NT - 1));
  adj[idx] = adj[idx] / fmaxf(finalcs[c], 1e-12f);
}

// C[M][64] (f32, atomic) += Arows(bf16 [M][K]) . Brows(bf16 [64][K]) over K-chunk
__global__ __launch_bounds__(256, 2) void k_gemmT(const bf16_t* __restrict__ A,
                                                  const bf16_t* __restrict__ Bt,
                                                  float* __restrict__ C, int K, int kchunk) {
  int tid = threadIdx.x, lane = tid & 63, w = tid >> 6;
  int rq = lane & 15, kq = lane >> 4;
  int r0 = blockIdx.x * 128 + w * 32;
  int kb = blockIdx.y * kchunk;
  f32x4 acc[2][4];
#pragma unroll
  for (int i = 0; i < 2; ++i)
#pragma unroll
    for (int j = 0; j < 4; ++j) acc[i][j] = 0.f;
  const bf16_t* Ap = A + (size_t)(r0 + rq) * K + kb + kq * 8;
  const bf16_t* Bp = Bt + (size_t)rq * K + kb + kq * 8;
#pragma unroll 2
  for (int kc = 0; kc < kchunk; kc += 32) {
    bf16x8 a[2], b[4];
#pragma unroll
    for (int f = 0; f < 2; ++f) a[f] = *(const bf16x8*)(Ap + (size_t)(f * 16) * K + kc);
#pragma unroll
    for (int f = 0; f < 4; ++f) b[f] = *(const bf16x8*)(Bp + (size_t)(f * 16) * K + kc);
#pragma unroll
    for (int fi = 0; fi < 2; ++fi)
#pragma unroll
      for (int fj = 0; fj < 4; ++fj)
        acc[fi][fj] = mfma_bf16(a[fi], b[fj], acc[fi][fj]);
  }
#pragma unroll
  for (int fi = 0; fi < 2; ++fi)
#pragma unroll
    for (int fj = 0; fj < 4; ++fj)
#pragma unroll
      for (int reg = 0; reg < 4; ++reg) {
        int row = r0 + fi * 16 + kq * 4 + reg;
        int col = fj * 16 + rq;
        atomicAdd(&C[(size_t)row * 64 + col], acc[fi][fj][reg]);
      }
}

// ---------------- f32 tile GEMMs (precision-sensitive tail) ----------------

__global__ __launch_bounds__(256) void k_gemm_n64(const float* __restrict__ A, int K,
                                                  const float* __restrict__ B,
                                                  float* __restrict__ C,
                                                  const float* __restrict__ bias, int relu) {
  __shared__ float As[64][68], Bs[64][68];
  int r0 = blockIdx.x * 64;
  int tid = threadIdx.x, tx = tid & 15, ty = tid >> 4;
  float acc[4][4] = {};
  for (int kc = 0; kc < K; kc += 64) {
    __syncthreads();
#pragma unroll
    for (int m = 0; m < 16; ++m) {
      int lin = tid + 256 * m;
      int row = lin >> 6, col = lin & 63;
      As[col][row] = A[(size_t)(r0 + row) * K + kc + col];
      Bs[row][col] = B[(size_t)(kc + row) * 64 + col];
    }
    __syncthreads();
#pragma unroll 8
    for (int k = 0; k < 64; ++k) {
      float a[4], b[4];
#pragma unroll
      for (int i = 0; i < 4; ++i) a[i] = As[k][ty * 4 + i];
#pragma unroll
      for (int j = 0; j < 4; ++j) b[j] = Bs[k][tx * 4 + j];
#pragma unroll
      for (int i = 0; i < 4; ++i)
#pragma unroll
        for (int j = 0; j < 4; ++j)
          acc[i][j] = fmaf(a[i], b[j], acc[i][j]);
    }
  }
#pragma unroll
  for (int i = 0; i < 4; ++i)
#pragma unroll
    for (int j = 0; j < 4; ++j) {
      float v = acc[i][j];
      if (bias) v += bias[tx * 4 + j];
      if (relu) v = fmaxf(v, 0.f);
      C[(size_t)(r0 + ty * 4 + i) * 64 + tx * 4 + j] = v;
    }
}

// split-K f32: C[M][64] += A[M][K-chunk] @ B[K][64]  (atomic)
__global__ __launch_bounds__(256) void k_gemm_n64_sk(const float* __restrict__ A, int K,
                                                     int kchunk, const float* __restrict__ B,
                                                     float* __restrict__ C) {
  __shared__ float As[64][68], Bs[64][68];
  int r0 = blockIdx.x * 64;
  int kb = blockIdx.y * kchunk;
  int tid = threadIdx.x, tx = tid & 15, ty = tid >> 4;
  float acc[4][4] = {};
  for (int kc = kb; kc < kb + kchunk; kc += 64) {
    __syncthreads();
#pragma unroll
    for (int m = 0; m < 16; ++m) {
      int lin = tid + 256 * m;
      int row = lin >> 6, col = lin & 63;
      As[col][row] = A[(size_t)(r0 + row) * K + kc + col];
      Bs[row][col] = B[(size_t)(kc + row) * 64 + col];
    }
    __syncthreads();
#pragma unroll 8
    for (int k = 0; k < 64; ++k) {
      float a[4], b[4];
#pragma unroll
      for (int i = 0; i < 4; ++i) a[i] = As[k][ty * 4 + i];
#pragma unroll
      for (int j = 0; j < 4; ++j) b[j] = Bs[k][tx * 4 + j];
#pragma unroll
      for (int i = 0; i < 4; ++i)
#pragma unroll
        for (int j = 0; j < 4; ++j)
          acc[i][j] = fmaf(a[i], b[j], acc[i][j]);
    }
  }
#pragma unroll
  for (int i = 0; i < 4; ++i)
#pragma unroll
    for (int j = 0; j < 4; ++j)
      atomicAdd(&C[(size_t)(r0 + ty * 4 + i) * 64 + tx * 4 + j], acc[i][j]);
}

__global__ void k_bias_relu(float* __restrict__ X, const float* __restrict__ b) {
  int idx = blockIdx.x * 256 + threadIdx.x;
  int e = idx & 63;
  X[idx] = fmaxf(X[idx] + b[e], 0.f);
}

// P2[r,0:3] = X1[r,:] @ W2
__global__ void k_p2(const float* __restrict__ X1, const float* __restrict__ W2,
                     float* __restrict__ P2) {
  int r = blockIdx.x * 64 + threadIdx.x;
  float a0 = 0.f, a1 = 0.f, a2 = 0.f;
#pragma unroll 8
  for (int k = 0; k < 64; ++k) {
    float x = X1[(size_t)r * 64 + k];
    a0 = fmaf(x, W2[k * 3 + 0], a0);
    a1 = fmaf(x, W2[k * 3 + 1], a1);
    a2 = fmaf(x, W2[k * 3 + 2], a2);
  }
  P2[r * 4 + 0] = a0; P2[r * 4 + 1] = a1; P2[r * 4 + 2] = a2;
}

// logits[r,:] = log_softmax(adj[r,:] @ P2 + b2)
__global__ void k_out(const float* __restrict__ adj, const float* __restrict__ P2,
                      const float* __restrict__ b2, float* __restrict__ logits) {
  int r = blockIdx.x, t = threadIdx.x;  // 64 threads
  const float* arow = adj + (size_t)r * NT;
  float a0 = 0.f, a1 = 0.f, a2 = 0.f;
  for (int c = t; c < NT; c += 64) {
    float a = arow[c];
    a0 = fmaf(a, P2[c * 4 + 0], a0);
    a1 = fmaf(a, P2[c * 4 + 1], a1);
    a2 = fmaf(a, P2[c * 4 + 2], a2);
  }
  for (int off = 32; off; off >>= 1) {
    a0 += __shfl_xor(a0, off);
    a1 += __shfl_xor(a1, off);
    a2 += __shfl_xor(a2, off);
  }
  if (t == 0) {
    a0 += b2[0]; a1 += b2[1]; a2 += b2[2];
    float m = fmaxf(a0, fmaxf(a1, a2));
    float lse = m + logf(expf(a0 - m) + expf(a1 - m) + expf(a2 - m));
    logits[r * 3 + 0] = a0 - lse;
    logits[r * 3 + 1] = a1 - lse;
    logits[r * 3 + 2] = a2 - lse;
  }
}

// ---------------- host ----------------

extern "C" void kernel_launch(void* const* d_in, const int* in_sizes, int n_in,
                              void* d_out, int out_size, void* d_ws, size_t ws_size,
                              hipStream_t stream) {
  (void)in_sizes; (void)n_in; (void)out_size; (void)ws_size;
  const float* features = (const float*)d_in[0];
  const float* adj      = (const float*)d_in[1];
  const float* mp_pap   = (const float*)d_in[2];
  const float* mp_psp   = (const float*)d_in[3];
  const float* fgo_w    = (const float*)d_in[6];
  const float* fpo_w    = (const float*)d_in[7];
  const float* sgg_pap_w = (const float*)d_in[8];
  const float* sgg_psp_w = (const float*)d_in[9];
  const float* sg_agg_w  = (const float*)d_in[10];
  const float* f_agg_f_w = (const float*)d_in[11];
  const float* f_agg_w   = (const float*)d_in[12];
  const float* topo_W_a  = (const float*)d_in[13];
  const float* topo_b_a  = (const float*)d_in[14];
  const float* topo_W_s  = (const float*)d_in[15];
  const float* topo_b_s  = (const float*)d_in[16];
  const float* fgt_w_a   = (const float*)d_in[17];
  const float* fgt_w_s   = (const float*)d_in[18];
  const float* gcn_W1    = (const float*)d_in[19];
  const float* gcn_b1    = (const float*)d_in[20];
  const float* gcn_W2    = (const float*)d_in[21];
  const float* gcn_b2    = (const float*)d_in[22];

  float* logits = (float*)d_out;
  float* adjOut = (float*)d_out + (size_t)NT * 3;      // 4096x4096 f32 output
  bf16_t* simA  = (bf16_t*)adjOut;                     // scratch lifetime before combine

  float* ws = (float*)d_ws;
  size_t o = 0;
  bf16_t* Vg   = (bf16_t*)(ws + o); o += (size_t)NT * 128;   // NT x 256 bf16
  bf16_t* Vfa  = (bf16_t*)(ws + o); o += (size_t)NA * 128;
  bf16_t* Vf0  = (bf16_t*)(ws + o); o += (size_t)NT * 128;
  bf16_t* Vf1  = (bf16_t*)(ws + o); o += (size_t)NT * 128;
  bf16_t* Vpap = (bf16_t*)(ws + o); o += (size_t)NT * 64;    // NT x 128 bf16
  bf16_t* Vpsp = (bf16_t*)(ws + o); o += (size_t)NT * 64;
  bf16_t* Vs0  = (bf16_t*)(ws + o); o += (size_t)NT * 64;
  bf16_t* Vs1  = (bf16_t*)(ws + o); o += (size_t)NT * 64;
  bf16_t* Vfs  = (bf16_t*)(ws + o); o += (size_t)NS * 128;
  bf16_t* simS = (bf16_t*)(ws + o); o += (size_t)NS * NS / 2;
  bf16_t* WaT  = (bf16_t*)(ws + o); o += (size_t)64 * NA / 2;
  bf16_t* WsT  = (bf16_t*)(ws + o); o += (size_t)64 * NS / 2;
  float* fpa  = ws + o; o += (size_t)NT * 128;
  float* fps  = ws + o; o += (size_t)NT * 128;
  float* Sa   = ws + o; o += (size_t)NA * 64;   // zeroed (atomic target)
  float* Ss   = ws + o; o += (size_t)NS * 64;   // contiguous with Sa
  float* topoA = ws + o; o += (size_t)NT * 64;
  float* topoS = ws + o; o += (size_t)NT * 64;
  float* H1   = ws + o; o += (size_t)NT * 64;
  float* X1   = ws + o; o += (size_t)NT * 64;   // zeroed (atomic target)
  float* P2   = ws + o; o += (size_t)NT * 4;
  float* cs   = ws + o; o += (size_t)7 * NT;    // zeroed
  float* fcs  = ws + o; o += NT;                // contiguous with cs
  float* coef = ws + o; o += (size_t)7 * NT;
  float* w8   = ws + o; o += 8;

  hipMemsetAsync(cs, 0, (size_t)8 * NT * sizeof(float), stream);
  hipMemsetAsync(Sa, 0, (size_t)(NA + NS) * 64 * sizeof(float), stream);
  hipMemsetAsync(X1, 0, (size_t)NT * 64 * sizeof(float), stream);
  k_weights<<<1, 1, 0, stream>>>(sg_agg_w, f_agg_f_w, f_agg_w, w8);

  // normalized head-weighted feature vectors (bf16)
  k_rownorm<<<NT, 64, 0, stream>>>(features, 128, fgo_w, Vg);
  k_rownorm<<<NT, 64, 0, stream>>>(mp_pap, 64, sgg_pap_w, Vpap);
  k_rownorm<<<NT, 64, 0, stream>>>(mp_psp, 64, sgg_psp_w, Vpsp);
  k_rownorm<<<NA, 64, 0, stream>>>(features + (size_t)NT * 128, 128, fgo_w, Vfa);
  k_rownorm<<<NS, 64, 0, stream>>>(features + (size_t)(NT + NA) * 128, 128, fgo_w, Vfs);

  // feat_prop = ori_g @ fmat_r  (sparse ballot-scan)
  k_spmm128<<<NT, 128, 0, stream>>>(adj, NT, NA, features + (size_t)NT * 128, fpa);
  k_spmm128<<<NT, 128, 0, stream>>>(adj, NT + NA, NS, features + (size_t)(NT + NA) * 128, fps);
  k_rownorm<<<NT, 64, 0, stream>>>(fpa, 128, fpo_w, Vf0);
  k_rownorm<<<NT, 64, 0, stream>>>(fps, 128, fpo_w, Vf1);

  // topo weight transposes (bf16 rows)
  k_transp<<<(NA * 64) / 256, 256, 0, stream>>>(topo_W_a, NA, WaT);
  k_transp<<<(NS * 64) / 256, 256, 0, stream>>>(topo_W_s, NS, WsT);

  // sim_r (thresholded, bf16) and S_r = sim_r @ topo_W (MFMA split-K, atomic f32)
  k_gram_sim<<<dim3(NA / 128, NA / 128), 256, 0, stream>>>(Vfa, NA, 256, 0.1f, simA);
  k_gram_sim<<<dim3(NS / 128, NS / 128), 256, 0, stream>>>(Vfs, NS, 256, 0.1f, simS);
  k_gemmT<<<dim3(NA / 128, 8), 256, 0, stream>>>(simA, WaT, Sa, NA, NA / 8);
  k_gemmT<<<dim3(NS / 128, 8), 256, 0, stream>>>(simS, WsT, Ss, NS, NS / 8);

  // topo_hid = ori_g @ S_r + b
  k_spmm64<<<NT, 128, 0, stream>>>(adj, NT, NA, Sa, topo_b_a, topoA);
  k_spmm64<<<NT, 128, 0, stream>>>(adj, NT + NA, NS, Ss, topo_b_s, topoS);
  k_rownorm<<<NT, 64, 0, stream>>>(topoA, 64, fgt_w_a, Vs0);
  k_rownorm<<<NT, 64, 0, stream>>>(topoS, 64, fgt_w_s, Vs1);

  // pass 1: per-channel column sums (MFMA) -> coefficients
  k_colsum_all<<<dim3(NT / 128, NT / 128), 256, 0, stream>>>(Vg, Vpap, Vpsp, Vf0, Vf1, Vs0, Vs1, cs);
  k_coef<<<NT / 256, 256, 0, stream>>>(cs, w8, coef);

  // pass 2: combine + symmetrize (overwrites simA scratch with final f32 adj)
  k_combine<<<dim3(NT / 128, NT / 128), 256, 0, stream>>>(Vg, Vpap, Vpsp, Vf0, Vf1, Vs0, Vs1,
                                                          coef, adjOut, fcs);
  k_scale<<<(NT * NT) / 256, 256, 0, stream>>>(adjOut, fcs);

  // GCN (f32 tail)
  k_gemm_n64<<<NT / 64, 256, 0, stream>>>(features, 128, gcn_W1, H1, nullptr, 0);
  k_gemm_n64_sk<<<dim3(NT / 64, 8), 256, 0, stream>>>(adjOut, NT, NT / 8, H1, X1);
  k_bias_relu<<<(NT * 64) / 256, 256, 0, stream>>>(X1, gcn_b1);
  k_p2<<<NT / 64, 64, 0, stream>>>(X1, gcn_W2, P2);
  k_out<<<NT, 64, 0, stream>>>(adjOut, P2, gcn_b2, logits);
}